// Round 1
// baseline (69.515 us; speedup 1.0000x reference)
//
#include <hip/hip_runtime.h>
#include <hip/hip_bf16.h>

// Problem constants (from reference): B=32, Q_LOG=Q_PHYS=256, E=4096.
#define NB   32
#define NQ   256
#define NE   4096
#define MROWS (NB * NQ)   // 8192 flattened rows of P / M

// Static scratch (safe regardless of ws_size): M = Pflat @ d_swap, and per-edge values.
__device__ float g_M[MROWS * NQ];        // 8.39 MB
__device__ float g_edge_val[NE];         // weighted per-edge cost (already * w_e / B)

// ---------------------------------------------------------------------------
// K1: Mflat(8192x256) = Pflat(8192x256) @ Dsw(256x256), Dsw = 3*max(d_hw-1,0)
// 64x64 tile per block, K-step 16, 256 threads, 4x4 register blocking.
// ---------------------------------------------------------------------------
__global__ __launch_bounds__(256) void gemm_pd_kernel(const float* __restrict__ P,
                                                      const float* __restrict__ d_hw) {
    __shared__ float As[16][65];   // [kk][row] padded -> conflict-free writes
    __shared__ float Bs[16][64];   // [kk][col]

    const int colTile = blockIdx.x;        // 0..3
    const int rowTile = blockIdx.y;        // 0..127
    const int rowBase = rowTile * 64;
    const int colBase = colTile * 64;

    const int tid = threadIdx.x;
    const int tx = tid & 15;               // 0..15 (col group)
    const int ty = tid >> 4;               // 0..15 (row group)

    float acc[4][4];
#pragma unroll
    for (int r = 0; r < 4; ++r)
#pragma unroll
        for (int c = 0; c < 4; ++c) acc[r][c] = 0.f;

    for (int k0 = 0; k0 < NQ; k0 += 16) {
        // Load A tile: 64 rows x 16 k
        {
            const int kk = tid & 15;
            const int r0 = tid >> 4;       // 0..15
#pragma unroll
            for (int it = 0; it < 4; ++it) {
                const int r = r0 + it * 16;
                As[kk][r] = P[(rowBase + r) * NQ + k0 + kk];
            }
        }
        // Load B tile: 16 k x 64 cols, apply d_swap transform on the fly
        {
            const int c = tid & 63;
            const int kk0 = tid >> 6;      // 0..3
#pragma unroll
            for (int it = 0; it < 4; ++it) {
                const int kk = kk0 + it * 4;
                float d = d_hw[(k0 + kk) * NQ + colBase + c];
                d = d - 1.0f;
                d = d > 0.f ? 3.0f * d : 0.f;
                Bs[kk][c] = d;
            }
        }
        __syncthreads();

#pragma unroll
        for (int kk = 0; kk < 16; ++kk) {
            float a0 = As[kk][ty];
            float a1 = As[kk][ty + 16];
            float a2 = As[kk][ty + 32];
            float a3 = As[kk][ty + 48];
            float b0 = Bs[kk][tx];
            float b1 = Bs[kk][tx + 16];
            float b2 = Bs[kk][tx + 32];
            float b3 = Bs[kk][tx + 48];
            acc[0][0] += a0 * b0; acc[0][1] += a0 * b1; acc[0][2] += a0 * b2; acc[0][3] += a0 * b3;
            acc[1][0] += a1 * b0; acc[1][1] += a1 * b1; acc[1][2] += a1 * b2; acc[1][3] += a1 * b3;
            acc[2][0] += a2 * b0; acc[2][1] += a2 * b1; acc[2][2] += a2 * b2; acc[2][3] += a2 * b3;
            acc[3][0] += a3 * b0; acc[3][1] += a3 * b1; acc[3][2] += a3 * b2; acc[3][3] += a3 * b3;
        }
        __syncthreads();
    }

#pragma unroll
    for (int r = 0; r < 4; ++r) {
        const int row = rowBase + ty + 16 * r;
#pragma unroll
        for (int c = 0; c < 4; ++c) {
            const int col = colBase + tx + 16 * c;
            g_M[row * NQ + col] = acc[r][c];
        }
    }
}

// ---------------------------------------------------------------------------
// K2: one block per edge. val[e] = w_e * (1/B) * sum_b dot(M[b,i_e,:], P[b,j_e,:])
// 256 threads = 4 lane-groups of 64; group g handles batches b = g, g+4, ...
// float4 loads: 64 lanes x 16B = one full 1KB row per iteration.
// ---------------------------------------------------------------------------
__global__ __launch_bounds__(256) void edge_kernel(const float* __restrict__ P,
                                                   const int* __restrict__ edge_i,
                                                   const int* __restrict__ edge_j,
                                                   const float* __restrict__ edge_w) {
    const int e = blockIdx.x;
    const int i = edge_i[e];
    const int j = edge_j[e];

    const int tid = threadIdx.x;
    const int grp = tid >> 6;   // 0..3
    const int lane = tid & 63;  // 0..63

    float acc = 0.f;
    for (int b = grp; b < NB; b += 4) {
        const float4* mrow = (const float4*)&g_M[((b << 8) + i) << 8];
        const float4* prow = (const float4*)&P[((b << 8) + j) << 8];
        float4 mv = mrow[lane];
        float4 pv = prow[lane];
        acc += mv.x * pv.x + mv.y * pv.y + mv.z * pv.z + mv.w * pv.w;
    }

    // wave (64-lane) reduction
#pragma unroll
    for (int off = 32; off > 0; off >>= 1) acc += __shfl_down(acc, off);

    __shared__ float partial[4];
    if (lane == 0) partial[grp] = acc;
    __syncthreads();
    if (tid == 0) {
        float tot = partial[0] + partial[1] + partial[2] + partial[3];
        g_edge_val[e] = edge_w[e] * (tot * (1.0f / NB));
    }
}

// ---------------------------------------------------------------------------
// K3: single-block deterministic final reduction.
// ---------------------------------------------------------------------------
__global__ __launch_bounds__(256) void finalize_kernel(const float* __restrict__ edge_w,
                                                       float* __restrict__ out) {
    const int tid = threadIdx.x;
    float num = 0.f, den = 0.f;
    for (int e = tid; e < NE; e += 256) {
        num += g_edge_val[e];
        den += edge_w[e];
    }
#pragma unroll
    for (int off = 32; off > 0; off >>= 1) {
        num += __shfl_down(num, off);
        den += __shfl_down(den, off);
    }
    __shared__ float pn[4], pd[4];
    const int wid = tid >> 6;
    if ((tid & 63) == 0) { pn[wid] = num; pd[wid] = den; }
    __syncthreads();
    if (tid == 0) {
        float n = pn[0] + pn[1] + pn[2] + pn[3];
        float d = pd[0] + pd[1] + pd[2] + pd[3];
        d = d > 1e-8f ? d : 1e-8f;
        out[0] = n / d;
    }
}

extern "C" void kernel_launch(void* const* d_in, const int* in_sizes, int n_in,
                              void* d_out, int out_size, void* d_ws, size_t ws_size,
                              hipStream_t stream) {
    const float* P      = (const float*)d_in[0];
    const float* d_hw   = (const float*)d_in[1];
    const int*   edge_i = (const int*)d_in[2];
    const int*   edge_j = (const int*)d_in[3];
    const float* edge_w = (const float*)d_in[4];
    float* out = (float*)d_out;

    dim3 gemmGrid(4, 128);
    gemm_pd_kernel<<<gemmGrid, 256, 0, stream>>>(P, d_hw);
    edge_kernel<<<NE, 256, 0, stream>>>(P, edge_i, edge_j, edge_w);
    finalize_kernel<<<1, 256, 0, stream>>>(edge_w, out);
}

// Round 4
// 63.933 us; speedup vs baseline: 1.0873x; 1.0873x over previous
//
#include <hip/hip_runtime.h>
#include <hip/hip_bf16.h>

// Problem constants: B=32, Q_LOG=Q_PHYS=256, E=4096.
#define NB   32
#define NQ   256
#define NE   4096
#define MROWS (NB * NQ)   // 8192 flattened rows of P / M

// Static scratch: M = Pflat @ Dsw, C[b] = M[b] @ P[b]^T, per-edge values.
__device__ float g_M[MROWS * NQ];        // 8.39 MB
__device__ float g_C[NB * NQ * NQ];      // 8.39 MB
__device__ float g_edge_val[NE];

// ---------------------------------------------------------------------------
// K1: Mflat(8192x256) = Pflat(8192x256) @ Dsw(256x256), Dsw = 3*max(d_hw-1,0)
// 64x64 tile, K-step 16, 256 threads, contiguous 4x4 blocking, b128 LDS reads.
// ---------------------------------------------------------------------------
__global__ __launch_bounds__(256) void gemm_pd_kernel(const float* __restrict__ P,
                                                      const float* __restrict__ d_hw) {
    __shared__ float As[16][68];   // [kk][row], 68 pad -> 16B-aligned rows, <=2-way banks
    __shared__ float Bs[16][68];   // [kk][col]

    const int colBase = blockIdx.x * 64;
    const int rowBase = blockIdx.y * 64;

    const int tid = threadIdx.x;
    const int tx = tid & 15;               // col group (4 cols)
    const int ty = tid >> 4;               // row group (4 rows)

    float acc[4][4];
#pragma unroll
    for (int r = 0; r < 4; ++r)
#pragma unroll
        for (int c = 0; c < 4; ++c) acc[r][c] = 0.f;

    const int lrow = tid >> 2;             // 0..63  (A-stage row)
    const int lkq  = (tid & 3) * 4;        // 0,4,8,12 (A-stage k quad)
    const int bkk  = tid >> 4;             // 0..15  (B-stage k row)
    const int bcq  = (tid & 15) * 4;       // B-stage col quad

    for (int k0 = 0; k0 < NQ; k0 += 16) {
        // A tile: 64 rows x 16 k, one float4 per thread
        {
            float4 v = *(const float4*)&P[(rowBase + lrow) * NQ + k0 + lkq];
            As[lkq + 0][lrow] = v.x;
            As[lkq + 1][lrow] = v.y;
            As[lkq + 2][lrow] = v.z;
            As[lkq + 3][lrow] = v.w;
        }
        // B tile: 16 k x 64 cols, transform on the fly
        {
            float4 v = *(const float4*)&d_hw[(k0 + bkk) * NQ + colBase + bcq];
            float4 o;
            o.x = v.x > 1.f ? 3.f * (v.x - 1.f) : 0.f;
            o.y = v.y > 1.f ? 3.f * (v.y - 1.f) : 0.f;
            o.z = v.z > 1.f ? 3.f * (v.z - 1.f) : 0.f;
            o.w = v.w > 1.f ? 3.f * (v.w - 1.f) : 0.f;
            *(float4*)&Bs[bkk][bcq] = o;
        }
        __syncthreads();

#pragma unroll
        for (int kk = 0; kk < 16; ++kk) {
            float4 av = *(const float4*)&As[kk][ty * 4];
            float4 bv = *(const float4*)&Bs[kk][tx * 4];
            float ar[4] = {av.x, av.y, av.z, av.w};
            float br[4] = {bv.x, bv.y, bv.z, bv.w};
#pragma unroll
            for (int r = 0; r < 4; ++r)
#pragma unroll
                for (int c = 0; c < 4; ++c) acc[r][c] += ar[r] * br[c];
        }
        __syncthreads();
    }

#pragma unroll
    for (int r = 0; r < 4; ++r) {
        const int row = rowBase + ty * 4 + r;
        float4 o = make_float4(acc[r][0], acc[r][1], acc[r][2], acc[r][3]);
        *(float4*)&g_M[row * NQ + colBase + tx * 4] = o;
    }
}

// ---------------------------------------------------------------------------
// K2: C[b](256x256) = M[b](256x256) @ P[b]^T.  C[b,i,j] = sum_p M[b,i,p]P[b,j,p]
// grid (4 colTiles, 4 rowTiles, 32 batches). Both operands read row-wise (NT).
// ---------------------------------------------------------------------------
__global__ __launch_bounds__(256) void gemm_mpt_kernel(const float* __restrict__ P) {
    __shared__ float As[16][68];   // [kk][i-row]
    __shared__ float Bs[16][68];   // [kk][j-row]

    const int colBase = blockIdx.x * 64;   // j
    const int rowBase = blockIdx.y * 64;   // i
    const int b = blockIdx.z;
    const int rowOff = b * NQ;             // flat row offset for batch b

    const int tid = threadIdx.x;
    const int tx = tid & 15;
    const int ty = tid >> 4;

    float acc[4][4];
#pragma unroll
    for (int r = 0; r < 4; ++r)
#pragma unroll
        for (int c = 0; c < 4; ++c) acc[r][c] = 0.f;

    const int lrow = tid >> 2;             // 0..63
    const int lkq  = (tid & 3) * 4;        // 0,4,8,12

    for (int k0 = 0; k0 < NQ; k0 += 16) {
        {
            float4 v = *(const float4*)&g_M[(rowOff + rowBase + lrow) * NQ + k0 + lkq];
            As[lkq + 0][lrow] = v.x;
            As[lkq + 1][lrow] = v.y;
            As[lkq + 2][lrow] = v.z;
            As[lkq + 3][lrow] = v.w;
        }
        {
            float4 v = *(const float4*)&P[(rowOff + colBase + lrow) * NQ + k0 + lkq];
            Bs[lkq + 0][lrow] = v.x;
            Bs[lkq + 1][lrow] = v.y;
            Bs[lkq + 2][lrow] = v.z;
            Bs[lkq + 3][lrow] = v.w;
        }
        __syncthreads();

#pragma unroll
        for (int kk = 0; kk < 16; ++kk) {
            float4 av = *(const float4*)&As[kk][ty * 4];
            float4 bv = *(const float4*)&Bs[kk][tx * 4];
            float ar[4] = {av.x, av.y, av.z, av.w};
            float br[4] = {bv.x, bv.y, bv.z, bv.w};
#pragma unroll
            for (int r = 0; r < 4; ++r)
#pragma unroll
                for (int c = 0; c < 4; ++c) acc[r][c] += ar[r] * br[c];
        }
        __syncthreads();
    }

#pragma unroll
    for (int r = 0; r < 4; ++r) {
        const int i = rowBase + ty * 4 + r;
        float4 o = make_float4(acc[r][0], acc[r][1], acc[r][2], acc[r][3]);
        *(float4*)&g_C[b * (NQ * NQ) + i * NQ + colBase + tx * 4] = o;
    }
}

// ---------------------------------------------------------------------------
// K3: per-edge gather: val[e] = w_e * (1/B) * sum_b C[b, i_e, j_e]
// ---------------------------------------------------------------------------
__global__ __launch_bounds__(256) void edge_gather_kernel(const int* __restrict__ edge_i,
                                                          const int* __restrict__ edge_j,
                                                          const float* __restrict__ edge_w) {
    const int e = blockIdx.x * 256 + threadIdx.x;
    const int i = edge_i[e];
    const int j = edge_j[e];
    const int base = i * NQ + j;
    float s = 0.f;
#pragma unroll
    for (int b = 0; b < NB; ++b) s += g_C[b * (NQ * NQ) + base];
    g_edge_val[e] = edge_w[e] * (s * (1.0f / NB));
}

// ---------------------------------------------------------------------------
// K4: single-block deterministic final reduction.
// ---------------------------------------------------------------------------
__global__ __launch_bounds__(256) void finalize_kernel(const float* __restrict__ edge_w,
                                                       float* __restrict__ out) {
    const int tid = threadIdx.x;
    float num = 0.f, den = 0.f;
    for (int e = tid; e < NE; e += 256) {
        num += g_edge_val[e];
        den += edge_w[e];
    }
#pragma unroll
    for (int off = 32; off > 0; off >>= 1) {
        num += __shfl_down(num, off);
        den += __shfl_down(den, off);
    }
    __shared__ float pn[4], pd[4];
    const int wid = tid >> 6;
    if ((tid & 63) == 0) { pn[wid] = num; pd[wid] = den; }
    __syncthreads();
    if (tid == 0) {
        float n = pn[0] + pn[1] + pn[2] + pn[3];
        float d = pd[0] + pd[1] + pd[2] + pd[3];
        d = d > 1e-8f ? d : 1e-8f;
        out[0] = n / d;
    }
}

extern "C" void kernel_launch(void* const* d_in, const int* in_sizes, int n_in,
                              void* d_out, int out_size, void* d_ws, size_t ws_size,
                              hipStream_t stream) {
    const float* P      = (const float*)d_in[0];
    const float* d_hw   = (const float*)d_in[1];
    const int*   edge_i = (const int*)d_in[2];
    const int*   edge_j = (const int*)d_in[3];
    const float* edge_w = (const float*)d_in[4];
    float* out = (float*)d_out;

    gemm_pd_kernel<<<dim3(4, 128), 256, 0, stream>>>(P, d_hw);
    gemm_mpt_kernel<<<dim3(4, 4, NB), 256, 0, stream>>>(P);
    edge_gather_kernel<<<NE / 256, 256, 0, stream>>>(edge_i, edge_j, edge_w);
    finalize_kernel<<<1, 256, 0, stream>>>(edge_w, out);
}

// Round 5
// 49.545 us; speedup vs baseline: 1.4031x; 1.2904x over previous
//
#include <hip/hip_runtime.h>
#include <hip/hip_bf16.h>

// Problem constants: B=32, Q_LOG=Q_PHYS=256, E=4096.
#define NB   32
#define NQ   256
#define NE   4096
#define MROWS (NB * NQ)   // 8192 flattened rows of P / M

typedef __attribute__((ext_vector_type(8))) short short8;  // 8 bf16 = 4 VGPRs
typedef __attribute__((ext_vector_type(4))) float f32x4;

#define MFMA(a, b, c) __builtin_amdgcn_mfma_f32_16x16x32_bf16((a), (b), (c), 0, 0, 0)

// Static scratch.
__device__ ushort g_Pbf[MROWS * NQ];     // P in bf16, row-major [b*256+q][p]   (4.2 MB)
__device__ ushort g_Mbf[MROWS * NQ];     // M = P @ Dsw in bf16                (4.2 MB)
__device__ ushort g_DbfT[NQ * NQ];       // Dsw^T in bf16                      (128 KB)
__device__ float  g_Ct[NB * NQ * NQ];    // C[b] col-major: [b][j][i]          (8.4 MB)
__device__ float  g_edge_val[NE];

// RNE float -> bf16 (inputs finite).
__device__ __forceinline__ ushort f2bf(float f) {
    unsigned u = __float_as_uint(f);
    u += 0x7fffu + ((u >> 16) & 1u);
    return (ushort)(u >> 16);
}

// ---------------------------------------------------------------------------
// K0: convert P to bf16; build Dsw^T = (3*max(d_hw-1,0))^T in bf16.
// Blocks 0..511: P (each thread 4x ushort4). Blocks 512..527: Dsw^T.
// ---------------------------------------------------------------------------
__global__ __launch_bounds__(256) void prep_kernel(const float* __restrict__ P,
                                                   const float* __restrict__ d_hw) {
    const int b = blockIdx.x;
    const int tid = threadIdx.x;
    if (b < 512) {
        const int gid = b * 256 + tid;
        const float4* Pv = (const float4*)P;
#pragma unroll
        for (int it = 0; it < 4; ++it) {
            const int i = gid + it * (512 * 256);
            float4 v = Pv[i];
            ushort4 o;
            o.x = f2bf(v.x); o.y = f2bf(v.y); o.z = f2bf(v.z); o.w = f2bf(v.w);
            ((ushort4*)g_Pbf)[i] = o;
        }
    } else {
        const int p0 = (b - 512) * 16;
#pragma unroll
        for (int pr = 0; pr < 16; ++pr) {
            const int p = p0 + pr;
            float d = d_hw[p * NQ + tid];
            float s = d > 1.f ? 3.f * (d - 1.f) : 0.f;
            g_DbfT[tid * NQ + p] = f2bf(s);
        }
    }
}

// ---------------------------------------------------------------------------
// K1: Mbf(8192x256) = Pbf @ Dsw  (NT with DbfT).  64x64 block tile, 4 waves,
// each wave a 32x32 tile = 2x2 of 16x16x32 MFMA. Fragments direct from global
// (L2/L3-resident). A-frag: row = lane&15, k = (lane>>4)*8 + j.
// ---------------------------------------------------------------------------
__global__ __launch_bounds__(256) void gemm1_kernel() {
    const int tid = threadIdx.x;
    const int wave = tid >> 6, lane = tid & 63;
    const int l15 = lane & 15, koff = (lane >> 4) * 8;
    const int rowBase = blockIdx.y * 64 + (wave >> 1) * 32;
    const int colBase = blockIdx.x * 64 + (wave & 1) * 32;

    const ushort* A0 = g_Pbf + (rowBase + l15) * NQ + koff;
    const ushort* A1 = A0 + 16 * NQ;
    const ushort* B0 = g_DbfT + (colBase + l15) * NQ + koff;
    const ushort* B1 = B0 + 16 * NQ;

    f32x4 acc00 = {0,0,0,0}, acc01 = {0,0,0,0}, acc10 = {0,0,0,0}, acc11 = {0,0,0,0};
#pragma unroll 4
    for (int k0 = 0; k0 < NQ; k0 += 32) {
        short8 a0 = *(const short8*)(A0 + k0);
        short8 a1 = *(const short8*)(A1 + k0);
        short8 b0 = *(const short8*)(B0 + k0);
        short8 b1 = *(const short8*)(B1 + k0);
        acc00 = MFMA(a0, b0, acc00);
        acc01 = MFMA(a0, b1, acc01);
        acc10 = MFMA(a1, b0, acc10);
        acc11 = MFMA(a1, b1, acc11);
    }

    // C/D layout: col = lane&15, row = (lane>>4)*4 + reg.
    const int orow = (lane >> 4) * 4;
#pragma unroll
    for (int i = 0; i < 4; ++i) {
        g_Mbf[(rowBase + orow + i) * NQ + colBase + l15]           = f2bf(acc00[i]);
        g_Mbf[(rowBase + orow + i) * NQ + colBase + 16 + l15]      = f2bf(acc01[i]);
        g_Mbf[(rowBase + 16 + orow + i) * NQ + colBase + l15]      = f2bf(acc10[i]);
        g_Mbf[(rowBase + 16 + orow + i) * NQ + colBase + 16 + l15] = f2bf(acc11[i]);
    }
}

// ---------------------------------------------------------------------------
// K2: C[b] = M[b] @ P[b]^T (NT, both row-major). Store col-major [b][j][i]
// so each accumulator writes one contiguous f32x4.
// ---------------------------------------------------------------------------
__global__ __launch_bounds__(256) void gemm2_kernel() {
    const int b = blockIdx.z;
    const int tid = threadIdx.x;
    const int wave = tid >> 6, lane = tid & 63;
    const int l15 = lane & 15, koff = (lane >> 4) * 8;
    const int iBase = blockIdx.y * 64 + (wave >> 1) * 32;
    const int jBase = blockIdx.x * 64 + (wave & 1) * 32;

    const ushort* A0 = g_Mbf + (b * NQ + iBase + l15) * NQ + koff;
    const ushort* A1 = A0 + 16 * NQ;
    const ushort* B0 = g_Pbf + (b * NQ + jBase + l15) * NQ + koff;
    const ushort* B1 = B0 + 16 * NQ;

    f32x4 acc00 = {0,0,0,0}, acc01 = {0,0,0,0}, acc10 = {0,0,0,0}, acc11 = {0,0,0,0};
#pragma unroll 4
    for (int k0 = 0; k0 < NQ; k0 += 32) {
        short8 a0 = *(const short8*)(A0 + k0);
        short8 a1 = *(const short8*)(A1 + k0);
        short8 b0 = *(const short8*)(B0 + k0);
        short8 b1 = *(const short8*)(B1 + k0);
        acc00 = MFMA(a0, b0, acc00);
        acc01 = MFMA(a0, b1, acc01);
        acc10 = MFMA(a1, b0, acc10);
        acc11 = MFMA(a1, b1, acc11);
    }

    const int orow = (lane >> 4) * 4;
    float* Cb = g_Ct + b * (NQ * NQ);
    *(f32x4*)&Cb[(jBase + l15) * NQ + iBase + orow]           = acc00;  // rows i, cols j
    *(f32x4*)&Cb[(jBase + 16 + l15) * NQ + iBase + orow]      = acc01;
    *(f32x4*)&Cb[(jBase + l15) * NQ + iBase + 16 + orow]      = acc10;
    *(f32x4*)&Cb[(jBase + 16 + l15) * NQ + iBase + 16 + orow] = acc11;
}

// ---------------------------------------------------------------------------
// K3: per-edge gather: val[e] = w_e * (1/B) * sum_b Ct[b, j_e, i_e]
// ---------------------------------------------------------------------------
__global__ __launch_bounds__(256) void edge_gather_kernel(const int* __restrict__ edge_i,
                                                          const int* __restrict__ edge_j,
                                                          const float* __restrict__ edge_w) {
    const int e = blockIdx.x * 256 + threadIdx.x;
    const int i = edge_i[e];
    const int j = edge_j[e];
    const int base = j * NQ + i;   // col-major per batch
    float s = 0.f;
#pragma unroll
    for (int b = 0; b < NB; ++b) s += g_Ct[b * (NQ * NQ) + base];
    g_edge_val[e] = edge_w[e] * (s * (1.0f / NB));
}

// ---------------------------------------------------------------------------
// K4: single-block deterministic final reduction.
// ---------------------------------------------------------------------------
__global__ __launch_bounds__(256) void finalize_kernel(const float* __restrict__ edge_w,
                                                       float* __restrict__ out) {
    const int tid = threadIdx.x;
    float num = 0.f, den = 0.f;
    for (int e = tid; e < NE; e += 256) {
        num += g_edge_val[e];
        den += edge_w[e];
    }
#pragma unroll
    for (int off = 32; off > 0; off >>= 1) {
        num += __shfl_down(num, off);
        den += __shfl_down(den, off);
    }
    __shared__ float pn[4], pd[4];
    const int wid = tid >> 6;
    if ((tid & 63) == 0) { pn[wid] = num; pd[wid] = den; }
    __syncthreads();
    if (tid == 0) {
        float n = pn[0] + pn[1] + pn[2] + pn[3];
        float d = pd[0] + pd[1] + pd[2] + pd[3];
        d = d > 1e-8f ? d : 1e-8f;
        out[0] = n / d;
    }
}

extern "C" void kernel_launch(void* const* d_in, const int* in_sizes, int n_in,
                              void* d_out, int out_size, void* d_ws, size_t ws_size,
                              hipStream_t stream) {
    const float* P      = (const float*)d_in[0];
    const float* d_hw   = (const float*)d_in[1];
    const int*   edge_i = (const int*)d_in[2];
    const int*   edge_j = (const int*)d_in[3];
    const float* edge_w = (const float*)d_in[4];
    float* out = (float*)d_out;

    prep_kernel<<<528, 256, 0, stream>>>(P, d_hw);
    gemm1_kernel<<<dim3(4, 128), 256, 0, stream>>>();
    gemm2_kernel<<<dim3(4, 4, NB), 256, 0, stream>>>();
    edge_gather_kernel<<<NE / 256, 256, 0, stream>>>(edge_i, edge_j, edge_w);
    finalize_kernel<<<1, 256, 0, stream>>>(edge_w, out);
}